// Round 2
// baseline (617.503 us; speedup 1.0000x reference)
//
#include <hip/hip_runtime.h>

typedef _Float16 half8 __attribute__((ext_vector_type(8)));
typedef float floatx4 __attribute__((ext_vector_type(4)));

#define NTOK 16384
#define DM   4096
#define NE   128
#define MT   32                  // tokens per tile
#define BK   64                  // k per iter
#define KSPLIT 2
#define KHALF (DM / KSPLIT)      // 2048
#define NITER (KHALF / BK)       // 32
#define NTILE (NTOK / MT)        // 512
#define NBLK  (NTILE * KSPLIT)   // 1024
#define TEMP 0.3f
#define CSTRIDE 528
#define ABUF (8 * CSTRIDE)
#define BUFSZ (2 * ABUF)
#define LSTRIDE 33               // logits [128][33] floats in LDS overlay

// ---------------- prep: pack wg into MFMA b-fragment order, f16x2 split ----------------
__global__ void pack_b_kernel(const float* __restrict__ wg, _Float16* __restrict__ Bp) {
    int gtid = blockIdx.x * blockDim.x + threadIdx.x;
    int l  = gtid & 63;
    int tg = gtid >> 6;
    int g  = tg & 7;
    int kc = tg >> 3;
    const float* src = wg + (size_t)(g * 16 + (l & 15)) * DM + kc * 32 + (l >> 4) * 8;
    float4 v0 = *(const float4*)src;
    float4 v1 = *(const float4*)(src + 4);
    float f[8] = {v0.x, v0.y, v0.z, v0.w, v1.x, v1.y, v1.z, v1.w};
    half8 h1, h2;
#pragma unroll
    for (int j = 0; j < 8; j++) {
        h1[j] = (_Float16)f[j];
        h2[j] = (_Float16)((f[j] - (float)h1[j]) * 2048.0f);
    }
    char* dst = (char*)Bp + (size_t)tg * 2048 + l * 16;
    *(half8*)dst = h1;
    *(half8*)(dst + 1024) = h2;
}

// ---------------- fused GEMM (K-split) + last-block top-2/softmax/me/ce ----------------
__device__ __forceinline__ void stage_write(unsigned char* base, unsigned off,
                                            float4 v0, float4 v1) {
    float f[8] = {v0.x, v0.y, v0.z, v0.w, v1.x, v1.y, v1.z, v1.w};
    half8 h1, h2;
#pragma unroll
    for (int j = 0; j < 8; j++) {
        h1[j] = (_Float16)f[j];
        h2[j] = (_Float16)((f[j] - (float)h1[j]) * 2048.0f);
    }
    *(half8*)(base + off) = h1;
    *(half8*)(base + ABUF + off) = h2;
}

__launch_bounds__(256, 4)
__global__ void moe_fused_kernel(const float* __restrict__ A,
                                 const _Float16* __restrict__ Bp,
                                 float* __restrict__ out,
                                 float* __restrict__ mece,
                                 float* __restrict__ part,
                                 int* __restrict__ cnt) {
    __shared__ __align__(16) unsigned char smem[2 * BUFSZ];
    __shared__ float tmax[MT], tscale[MT];
    __shared__ int sOld;
    float* LG = (float*)smem;            // overlay after main loop
    const int tid  = threadIdx.x;
    const int wave = tid >> 6;
    const int lane = tid & 63;
    const int quad = lane >> 4;
    const int lrow = lane & 15;
    const int tile = blockIdx.x & (NTILE - 1);
    const int half = blockIdx.x >> 9;    // pair (t, t+512): same XCD under round-robin
    const int tok0 = tile * MT;

    const int srow = tid >> 3;
    const int schunk = tid & 7;
    const float* aptr = A + (size_t)(tok0 + srow) * DM + half * KHALF + schunk * 8;
    const unsigned swoff = schunk * CSTRIDE + srow * 16;
    const unsigned aroff = quad * CSTRIDE + lrow * 16;

    const char* bB = (const char*)Bp + ((size_t)half << 20) + (wave * 2) * 2048 + lane * 16;

    floatx4 accm[2][2], accc[2][2];
#pragma unroll
    for (int r = 0; r < 2; r++)
#pragma unroll
        for (int c = 0; c < 2; c++) {
            accm[r][c] = (floatx4){0.f, 0.f, 0.f, 0.f};
            accc[r][c] = (floatx4){0.f, 0.f, 0.f, 0.f};
        }

    {
        float4 v0 = *(const float4*)aptr;
        float4 v1 = *(const float4*)(aptr + 4);
        stage_write(smem, swoff, v0, v1);
    }
    __syncthreads();

    for (int it = 0; it < NITER; ++it) {
        float4 n0, n1;
        if (it < NITER - 1) {
            const float* p = aptr + (it + 1) * BK;
            n0 = *(const float4*)p;
            n1 = *(const float4*)(p + 4);
        }
        unsigned char* cb = smem + (it & 1) * BUFSZ;
        const char* bit = bB + (size_t)it * 32768;

#pragma unroll
        for (int ks = 0; ks < 2; ++ks) {
            half8 b1f[2], b2f[2], a1[2], a2[2];
#pragma unroll
            for (int c = 0; c < 2; c++) {
                b1f[c] = *(const half8*)(bit + ks * 16384 + c * 2048);
                b2f[c] = *(const half8*)(bit + ks * 16384 + c * 2048 + 1024);
            }
#pragma unroll
            for (int r = 0; r < 2; r++) {
                a1[r] = *(const half8*)(cb + ks * 2112 + r * 256 + aroff);
                a2[r] = *(const half8*)(cb + ABUF + ks * 2112 + r * 256 + aroff);
            }
#pragma unroll
            for (int r = 0; r < 2; r++)
#pragma unroll
                for (int c = 0; c < 2; c++) {
                    accm[r][c] = __builtin_amdgcn_mfma_f32_16x16x32_f16(a1[r], b1f[c], accm[r][c], 0, 0, 0);
                    accc[r][c] = __builtin_amdgcn_mfma_f32_16x16x32_f16(a1[r], b2f[c], accc[r][c], 0, 0, 0);
                    accc[r][c] = __builtin_amdgcn_mfma_f32_16x16x32_f16(a2[r], b1f[c], accc[r][c], 0, 0, 0);
                }
        }
        if (it < NITER - 1)
            stage_write(smem + ((it + 1) & 1) * BUFSZ, swoff, n0, n1);
        __syncthreads();
    }

    // ---- combine split-f16 halves into this block's partial tile (registers) ----
    floatx4 v[2][2];
#pragma unroll
    for (int r = 0; r < 2; r++)
#pragma unroll
        for (int c = 0; c < 2; c++)
#pragma unroll
            for (int g = 0; g < 4; g++)
                v[r][c][g] = accm[r][c][g] + accc[r][c][g] * (1.0f / 2048.0f);

    // ---- store partial, then last-arriving block does the epilogue ----
    float* pslot = part + ((size_t)(half * NTILE + tile)) * (MT * NE);
#pragma unroll
    for (int r = 0; r < 2; r++)
#pragma unroll
        for (int c = 0; c < 2; c++) {
            const int e = wave * 32 + c * 16 + lrow;
            const int t = r * 16 + quad * 4;
            *(floatx4*)(pslot + e * MT + t) = v[r][c];
        }
    __threadfence();                       // release (agent scope)
    __syncthreads();
    if (tid == 0)
        sOld = __hip_atomic_fetch_add(&cnt[tile], 1, __ATOMIC_ACQ_REL, __HIP_MEMORY_SCOPE_AGENT);
    __syncthreads();
    if (sOld != 1) return;                 // first arrival: done
    __threadfence();                       // acquire: invalidate stale L1/L2 lines

    // ---- sum halves into LDS logits [NE][LSTRIDE], token-minor ----
    const float* oslot = part + ((size_t)((half ^ 1) * NTILE + tile)) * (MT * NE);
#pragma unroll
    for (int r = 0; r < 2; r++)
#pragma unroll
        for (int c = 0; c < 2; c++) {
            const int e = wave * 32 + c * 16 + lrow;
            const int t = r * 16 + quad * 4;
            floatx4 o = *(const floatx4*)(oslot + e * MT + t);
#pragma unroll
            for (int g = 0; g < 4; g++)
                LG[e * LSTRIDE + t + g] = v[r][c][g] + o[g];
        }
    __syncthreads();

    // ---- per-token top-2 + gate softmax (32 threads) ----
    if (tid < MT) {
        const int t = tid;
        float m1 = -1e30f, m2 = -1e30f;
        int i1 = 0, i2 = 0;
        for (int e = 0; e < NE; e++) {
            float vv = LG[e * LSTRIDE + t];
            if (vv > m1) { m2 = m1; i2 = i1; m1 = vv; i1 = e; }
            else if (vv > m2) { m2 = vv; i2 = e; }
        }
        float s = 0.f;
        for (int e = 0; e < NE; e++)
            s += __expf((LG[e * LSTRIDE + t] - m1) * (1.0f / TEMP));
        tmax[t] = m1;
        tscale[t] = 1.0f / s;

        const int tg = tok0 + t;
        out[tg * 2 + 0] = (float)i1;
        out[tg * 2 + 1] = (float)i2;
        float d = __expf(m2 - m1);
        float g1 = 1.0f / (1.0f + d);
        out[2 * NTOK + tg * 2 + 0] = g1;
        out[2 * NTOK + tg * 2 + 1] = d * g1;

        atomicAdd(&mece[NE + i1], 1.0f);   // ce count
    }
    __syncthreads();

    // ---- per-expert me partial (128 threads), accumulate globally ----
    if (tid < NE) {
        const int e = tid;
        float s = 0.f;
#pragma unroll
        for (int t = 0; t < MT; t++)
            s += __expf((LG[e * LSTRIDE + t] - tmax[t]) * (1.0f / TEMP)) * tscale[t];
        atomicAdd(&mece[e], s);
    }
}

// ---------------- finalize: loss from me/ce (256 floats) ----------------
__global__ void finalize_kernel(const float* __restrict__ mece, float* __restrict__ out) {
    __shared__ float w2[2];
    const int tid = threadIdx.x;   // 128
    float v = mece[tid] * mece[NE + tid] * ((float)NE / (float)NTOK);
#pragma unroll
    for (int off = 32; off; off >>= 1) v += __shfl_down(v, off);
    if ((tid & 63) == 0) w2[tid >> 6] = v;
    __syncthreads();
    if (tid == 0) out[4 * NTOK] = (w2[0] + w2[1]) / (float)NTOK;
}

extern "C" void kernel_launch(void* const* d_in, const int* in_sizes, int n_in,
                              void* d_out, int out_size, void* d_ws, size_t ws_size,
                              hipStream_t stream) {
    (void)in_sizes; (void)n_in; (void)out_size; (void)ws_size;
    const float* inp = (const float*)d_in[0];
    const float* wg  = (const float*)d_in[1];
    float* out = (float*)d_out;

    _Float16* Bp = (_Float16*)d_ws;                          // 2 MB packed B
    float* mece  = (float*)((char*)d_ws + (2u << 20));       // 256 floats: me[128], ce[128]
    int*   cnt   = (int*)(mece + 2 * NE);                    // 512 ints: per-tile arrival counters
    float* part  = (float*)((char*)d_ws + (4u << 20));       // 16 MB: [2][512][32*128] partials

    hipMemsetAsync(mece, 0, 2 * NE * sizeof(float) + NTILE * sizeof(int), stream);
    pack_b_kernel<<<256, 256, 0, stream>>>(wg, Bp);
    moe_fused_kernel<<<NBLK, 256, 0, stream>>>(inp, Bp, out, mece, part, cnt);
    finalize_kernel<<<1, NE, 0, stream>>>(mece, out);
}

// Round 3
// 561.896 us; speedup vs baseline: 1.0990x; 1.0990x over previous
//
#include <hip/hip_runtime.h>

typedef _Float16 half8 __attribute__((ext_vector_type(8)));
typedef float floatx4 __attribute__((ext_vector_type(4)));

#define NTOK 16384
#define DM   4096
#define NE   128
#define MT   32                   // tokens per GEMM tile
#define BK   64                   // k per iter
#define KSPLIT 4
#define KHALF (DM / KSPLIT)       // 1024
#define NITER (KHALF / BK)        // 16
#define NTILE (NTOK / MT)         // 512
#define NBLK  (NTILE * KSPLIT)    // 2048  -> 8 blocks/CU, 8 waves/SIMD
#define ET   64                   // tokens per epilogue block
#define NBLK_EPI (NTOK / ET)      // 256
#define TEMP 0.3f
#define CSTRIDE 528
#define ABUF (8 * CSTRIDE)
#define BUFSZ (2 * ABUF)
#define PSLOT (MT * NE)           // 4096 floats per (split, tile) partial

// ---------------- prep: pack wg into MFMA b-fragment order, f16x2 split ----------------
__global__ void pack_b_kernel(const float* __restrict__ wg, _Float16* __restrict__ Bp) {
    int gtid = blockIdx.x * blockDim.x + threadIdx.x;
    int l  = gtid & 63;
    int tg = gtid >> 6;
    int g  = tg & 7;
    int kc = tg >> 3;
    const float* src = wg + (size_t)(g * 16 + (l & 15)) * DM + kc * 32 + (l >> 4) * 8;
    float4 v0 = *(const float4*)src;
    float4 v1 = *(const float4*)(src + 4);
    float f[8] = {v0.x, v0.y, v0.z, v0.w, v1.x, v1.y, v1.z, v1.w};
    half8 h1, h2;
#pragma unroll
    for (int j = 0; j < 8; j++) {
        h1[j] = (_Float16)f[j];
        h2[j] = (_Float16)((f[j] - (float)h1[j]) * 2048.0f);
    }
    char* dst = (char*)Bp + (size_t)tg * 2048 + l * 16;
    *(half8*)dst = h1;
    *(half8*)(dst + 1024) = h2;
}

// ---------------- main GEMM (K-split 4-way, 8 blocks/CU) ----------------
__device__ __forceinline__ void stage_write(unsigned char* base, unsigned off,
                                            float4 v0, float4 v1) {
    float f[8] = {v0.x, v0.y, v0.z, v0.w, v1.x, v1.y, v1.z, v1.w};
    half8 h1, h2;
#pragma unroll
    for (int j = 0; j < 8; j++) {
        h1[j] = (_Float16)f[j];
        h2[j] = (_Float16)((f[j] - (float)h1[j]) * 2048.0f);
    }
    *(half8*)(base + off) = h1;
    *(half8*)(base + ABUF + off) = h2;
}

__launch_bounds__(256, 8)
__global__ void moe_gemm_kernel(const float* __restrict__ A,
                                const _Float16* __restrict__ Bp,
                                float* __restrict__ part) {
    __shared__ __align__(16) unsigned char smem[2 * BUFSZ];
    const int tid  = threadIdx.x;
    const int wave = tid >> 6;
    const int lane = tid & 63;
    const int quad = lane >> 4;
    const int lrow = lane & 15;
    const int tile = blockIdx.x & (NTILE - 1);
    const int half = blockIdx.x >> 9;          // 0..3 k-split
    const int tok0 = tile * MT;

    const int srow = tid >> 3;
    const int schunk = tid & 7;
    const float* aptr = A + (size_t)(tok0 + srow) * DM + half * KHALF + schunk * 8;
    const unsigned swoff = schunk * CSTRIDE + srow * 16;
    const unsigned aroff = quad * CSTRIDE + lrow * 16;

    // Bp quarter for this k-split: 32 kc-chunks * 8 groups * 2048 B = 512 KB
    const char* bB = (const char*)Bp + ((size_t)half << 19) + (wave * 2) * 2048 + lane * 16;

    floatx4 accm[2][2], accc[2][2];
#pragma unroll
    for (int r = 0; r < 2; r++)
#pragma unroll
        for (int c = 0; c < 2; c++) {
            accm[r][c] = (floatx4){0.f, 0.f, 0.f, 0.f};
            accc[r][c] = (floatx4){0.f, 0.f, 0.f, 0.f};
        }

    {
        float4 v0 = *(const float4*)aptr;
        float4 v1 = *(const float4*)(aptr + 4);
        stage_write(smem, swoff, v0, v1);
    }
    __syncthreads();

    for (int it = 0; it < NITER; ++it) {
        float4 n0, n1;
        if (it < NITER - 1) {
            const float* p = aptr + (it + 1) * BK;
            n0 = *(const float4*)p;
            n1 = *(const float4*)(p + 4);
        }
        unsigned char* cb = smem + (it & 1) * BUFSZ;
        const char* bit = bB + (size_t)it * 32768;

#pragma unroll
        for (int ks = 0; ks < 2; ++ks) {
            half8 b1f[2], b2f[2], a1[2], a2[2];
#pragma unroll
            for (int c = 0; c < 2; c++) {
                b1f[c] = *(const half8*)(bit + ks * 16384 + c * 2048);
                b2f[c] = *(const half8*)(bit + ks * 16384 + c * 2048 + 1024);
            }
#pragma unroll
            for (int r = 0; r < 2; r++) {
                a1[r] = *(const half8*)(cb + ks * 2112 + r * 256 + aroff);
                a2[r] = *(const half8*)(cb + ABUF + ks * 2112 + r * 256 + aroff);
            }
#pragma unroll
            for (int r = 0; r < 2; r++)
#pragma unroll
                for (int c = 0; c < 2; c++) {
                    accm[r][c] = __builtin_amdgcn_mfma_f32_16x16x32_f16(a1[r], b1f[c], accm[r][c], 0, 0, 0);
                    accc[r][c] = __builtin_amdgcn_mfma_f32_16x16x32_f16(a1[r], b2f[c], accc[r][c], 0, 0, 0);
                    accc[r][c] = __builtin_amdgcn_mfma_f32_16x16x32_f16(a2[r], b1f[c], accc[r][c], 0, 0, 0);
                }
        }
        if (it < NITER - 1)
            stage_write(smem + ((it + 1) & 1) * BUFSZ, swoff, n0, n1);
        __syncthreads();
    }

    // ---- store partial tile-local dense: part[half][tile][e][32] ----
    float* pslot = part + ((size_t)half * NTILE + tile) * PSLOT;
#pragma unroll
    for (int r = 0; r < 2; r++)
#pragma unroll
        for (int c = 0; c < 2; c++) {
            floatx4 v;
#pragma unroll
            for (int g = 0; g < 4; g++)
                v[g] = accm[r][c][g] + accc[r][c][g] * (1.0f / 2048.0f);
            const int e = wave * 32 + c * 16 + lrow;
            const int t = r * 16 + quad * 4;
            *(floatx4*)(pslot + e * MT + t) = v;    // 4 lanes fill each 64B line
        }
}

// ---------------- epilogue: sum 4 splits, top-2, softmax, me/ce ----------------
__global__ void topk_kernel(const float* __restrict__ part,
                            float* __restrict__ out,
                            float* __restrict__ mece) {
    __shared__ float LG[NE * 68];        // [128][68] token-minor
    __shared__ float tmax[ET], tscale[ET];
    __shared__ int hist[NE];
    const int tid = threadIdx.x;
    const int t0  = blockIdx.x * ET;

    // load + sum 4 split-partials: 4 threads per expert row, 2 passes of 64 experts
    {
        const int q = tid & 3;                         // q*16 tokens
        const size_t gtile = (size_t)(blockIdx.x * 2 + (q >> 1));
#pragma unroll
        for (int pass = 0; pass < 2; pass++) {
            const int e = (tid >> 2) + pass * 64;
            const size_t boff = gtile * PSLOT + e * MT + (q & 1) * 16;
            float* dst = LG + e * 68 + q * 16;
#pragma unroll
            for (int j = 0; j < 16; j += 4) {
                float4 s0 = *(const float4*)(part + 0 * NTILE * PSLOT + boff + j);
                float4 s1 = *(const float4*)(part + 1 * NTILE * PSLOT + boff + j);
                float4 s2 = *(const float4*)(part + 2 * NTILE * PSLOT + boff + j);
                float4 s3 = *(const float4*)(part + 3 * NTILE * PSLOT + boff + j);
                float4 s = {s0.x + s1.x + s2.x + s3.x,
                            s0.y + s1.y + s2.y + s3.y,
                            s0.z + s1.z + s2.z + s3.z,
                            s0.w + s1.w + s2.w + s3.w};
                *(float4*)(dst + j) = s;
            }
        }
    }
    if (tid < NE) hist[tid] = 0;
    __syncthreads();

    // per-token top-2 + gate softmax (64 threads)
    if (tid < ET) {
        const int t = tid;
        float m1 = -1e30f, m2 = -1e30f;
        int i1 = 0, i2 = 0;
        for (int e = 0; e < NE; e++) {
            float v = LG[e * 68 + t];
            if (v > m1) { m2 = m1; i2 = i1; m1 = v; i1 = e; }
            else if (v > m2) { m2 = v; i2 = e; }
        }
        float s = 0.f;
        for (int e = 0; e < NE; e++)
            s += __expf((LG[e * 68 + t] - m1) * (1.0f / TEMP));
        tmax[t] = m1;
        tscale[t] = 1.0f / s;
        atomicAdd(&hist[i1], 1);

        const int tg = t0 + t;
        out[tg * 2 + 0] = (float)i1;
        out[tg * 2 + 1] = (float)i2;
        float d = __expf(m2 - m1);
        float g1 = 1.0f / (1.0f + d);
        out[2 * NTOK + tg * 2 + 0] = g1;
        out[2 * NTOK + tg * 2 + 1] = d * g1;
    }
    __syncthreads();

    // per-expert me partial (128 threads) -> global atomics
    if (tid < NE) {
        const int e = tid;
        float s = 0.f;
#pragma unroll 4
        for (int t = 0; t < ET; t++)
            s += __expf((LG[e * 68 + t] - tmax[t]) * (1.0f / TEMP)) * tscale[t];
        atomicAdd(&mece[e], s);
        atomicAdd(&mece[NE + e], (float)hist[e]);
    }
}

// ---------------- finalize: loss from me/ce (256 floats) ----------------
__global__ void finalize_kernel(const float* __restrict__ mece, float* __restrict__ out) {
    __shared__ float w2[2];
    const int tid = threadIdx.x;   // 128
    float v = mece[tid] * mece[NE + tid] * ((float)NE / (float)NTOK);
#pragma unroll
    for (int off = 32; off; off >>= 1) v += __shfl_down(v, off);
    if ((tid & 63) == 0) w2[tid >> 6] = v;
    __syncthreads();
    if (tid == 0) out[4 * NTOK] = (w2[0] + w2[1]) / (float)NTOK;
}

extern "C" void kernel_launch(void* const* d_in, const int* in_sizes, int n_in,
                              void* d_out, int out_size, void* d_ws, size_t ws_size,
                              hipStream_t stream) {
    (void)in_sizes; (void)n_in; (void)out_size; (void)ws_size;
    const float* inp = (const float*)d_in[0];
    const float* wg  = (const float*)d_in[1];
    float* out = (float*)d_out;

    _Float16* Bp = (_Float16*)d_ws;                          // 2 MB packed B
    float* mece  = (float*)((char*)d_ws + (2u << 20));       // 256 floats: me[128], ce[128]
    float* part  = (float*)((char*)d_ws + (4u << 20));       // 32 MB: [4][512][128][32]

    hipMemsetAsync(mece, 0, 2 * NE * sizeof(float), stream);
    pack_b_kernel<<<256, 256, 0, stream>>>(wg, Bp);
    moe_gemm_kernel<<<NBLK, 256, 0, stream>>>(inp, Bp, part);
    topk_kernel<<<NBLK_EPI, 256, 0, stream>>>(part, out, mece);
    finalize_kernel<<<1, NE, 0, stream>>>(mece, out);
}

// Round 4
// 561.458 us; speedup vs baseline: 1.0998x; 1.0008x over previous
//
#include <hip/hip_runtime.h>

typedef _Float16 half8 __attribute__((ext_vector_type(8)));
typedef float floatx4 __attribute__((ext_vector_type(4)));

#define NTOK 16384
#define DM   4096
#define NE   128
#define MT   32                   // tokens per GEMM tile
#define BK   64                   // k per iter
#define KSPLIT 2
#define KHALF (DM / KSPLIT)       // 2048
#define NITER (KHALF / BK)        // 32
#define NTILE (NTOK / MT)         // 512
#define NBLK  (NTILE * KSPLIT)    // 1024
#define ET   64                   // tokens per epilogue block
#define NBLK_EPI (NTOK / ET)      // 256
#define TEMP 0.3f
#define PSLOT (MT * NE)           // 4096 floats per (split, tile) partial

// ---------------- prep: pack wg into MFMA b-fragment order, f16x2 split ----------------
__global__ void pack_b_kernel(const float* __restrict__ wg, _Float16* __restrict__ Bp) {
    int gtid = blockIdx.x * blockDim.x + threadIdx.x;
    int l  = gtid & 63;
    int tg = gtid >> 6;
    int g  = tg & 7;
    int kc = tg >> 3;
    const float* src = wg + (size_t)(g * 16 + (l & 15)) * DM + kc * 32 + (l >> 4) * 8;
    float4 v0 = *(const float4*)src;
    float4 v1 = *(const float4*)(src + 4);
    float f[8] = {v0.x, v0.y, v0.z, v0.w, v1.x, v1.y, v1.z, v1.w};
    half8 h1, h2;
#pragma unroll
    for (int j = 0; j < 8; j++) {
        h1[j] = (_Float16)f[j];
        h2[j] = (_Float16)((f[j] - (float)h1[j]) * 2048.0f);
    }
    char* dst = (char*)Bp + (size_t)tg * 2048 + l * 16;
    *(half8*)dst = h1;
    *(half8*)(dst + 1024) = h2;
}

// ---------------- main GEMM: barrier-free, LDS-free, direct A fragments ----------------
__device__ __forceinline__ void cvt8(float4 a, float4 b, half8* h1, half8* h2) {
    float f[8] = {a.x, a.y, a.z, a.w, b.x, b.y, b.z, b.w};
#pragma unroll
    for (int j = 0; j < 8; j++) {
        (*h1)[j] = (_Float16)f[j];
        (*h2)[j] = (_Float16)((f[j] - (float)(*h1)[j]) * 2048.0f);
    }
}

__launch_bounds__(256, 4)
__global__ void moe_gemm_kernel(const float* __restrict__ A,
                                const _Float16* __restrict__ Bp,
                                float* __restrict__ part) {
    const int tid  = threadIdx.x;
    const int wave = tid >> 6;
    const int lane = tid & 63;
    const int quad = lane >> 4;
    const int lrow = lane & 15;
    const int tile = blockIdx.x & (NTILE - 1);
    const int half = blockIdx.x >> 9;          // k-split 0/1
    const int tok0 = tile * MT;

    // per-lane A fragment base: row tok0+lrow (r adds 16 rows), col half*KHALF + quad*8
    const float* aB = A + (size_t)(tok0 + lrow) * DM + half * KHALF + quad * 8;
    const size_t RS = (size_t)16 * DM;         // r-stride in floats

    const char* bB = (const char*)Bp + ((size_t)half << 20) + (wave * 2) * 2048 + lane * 16;

    floatx4 accm[2][2], accc[2][2];
#pragma unroll
    for (int r = 0; r < 2; r++)
#pragma unroll
        for (int c = 0; c < 2; c++) {
            accm[r][c] = (floatx4){0.f, 0.f, 0.f, 0.f};
            accc[r][c] = (floatx4){0.f, 0.f, 0.f, 0.f};
        }

    // prefetch it=0 fragments (f32), [r][ks] as named regs: c<r><ks><a/b>
    float4 c00a = *(const float4*)(aB);
    float4 c00b = *(const float4*)(aB + 4);
    float4 c10a = *(const float4*)(aB + RS);
    float4 c10b = *(const float4*)(aB + RS + 4);
    float4 c01a = *(const float4*)(aB + 32);
    float4 c01b = *(const float4*)(aB + 36);
    float4 c11a = *(const float4*)(aB + RS + 32);
    float4 c11b = *(const float4*)(aB + RS + 36);

#pragma unroll 1
    for (int it = 0; it < NITER; ++it) {
        const float* ap = aB + (size_t)(it + 1) * BK;
        const char* bit = bB + (size_t)it * 32768;
        float4 n00a, n00b, n10a, n10b, n01a, n01b, n11a, n11b;

        // ---- ks = 0 ----
        {
            half8 a1[2], a2[2];
            cvt8(c00a, c00b, &a1[0], &a2[0]);
            cvt8(c10a, c10b, &a1[1], &a2[1]);
            if (it < NITER - 1) {              // issue next-iter ks0 loads (regs freed above)
                n00a = *(const float4*)(ap);
                n00b = *(const float4*)(ap + 4);
                n10a = *(const float4*)(ap + RS);
                n10b = *(const float4*)(ap + RS + 4);
            }
            half8 b1f[2], b2f[2];
#pragma unroll
            for (int c = 0; c < 2; c++) {
                b1f[c] = *(const half8*)(bit + c * 2048);
                b2f[c] = *(const half8*)(bit + c * 2048 + 1024);
            }
#pragma unroll
            for (int r = 0; r < 2; r++)
#pragma unroll
                for (int c = 0; c < 2; c++) {
                    accm[r][c] = __builtin_amdgcn_mfma_f32_16x16x32_f16(a1[r], b1f[c], accm[r][c], 0, 0, 0);
                    accc[r][c] = __builtin_amdgcn_mfma_f32_16x16x32_f16(a1[r], b2f[c], accc[r][c], 0, 0, 0);
                    accc[r][c] = __builtin_amdgcn_mfma_f32_16x16x32_f16(a2[r], b1f[c], accc[r][c], 0, 0, 0);
                }
        }

        // ---- ks = 1 ----
        {
            half8 a1[2], a2[2];
            cvt8(c01a, c01b, &a1[0], &a2[0]);
            cvt8(c11a, c11b, &a1[1], &a2[1]);
            if (it < NITER - 1) {              // issue next-iter ks1 loads
                n01a = *(const float4*)(ap + 32);
                n01b = *(const float4*)(ap + 36);
                n11a = *(const float4*)(ap + RS + 32);
                n11b = *(const float4*)(ap + RS + 36);
            }
            half8 b1f[2], b2f[2];
#pragma unroll
            for (int c = 0; c < 2; c++) {
                b1f[c] = *(const half8*)(bit + 16384 + c * 2048);
                b2f[c] = *(const half8*)(bit + 16384 + c * 2048 + 1024);
            }
#pragma unroll
            for (int r = 0; r < 2; r++)
#pragma unroll
                for (int c = 0; c < 2; c++) {
                    accm[r][c] = __builtin_amdgcn_mfma_f32_16x16x32_f16(a1[r], b1f[c], accm[r][c], 0, 0, 0);
                    accc[r][c] = __builtin_amdgcn_mfma_f32_16x16x32_f16(a1[r], b2f[c], accc[r][c], 0, 0, 0);
                    accc[r][c] = __builtin_amdgcn_mfma_f32_16x16x32_f16(a2[r], b1f[c], accc[r][c], 0, 0, 0);
                }
        }

        if (it < NITER - 1) {
            c00a = n00a; c00b = n00b; c10a = n10a; c10b = n10b;
            c01a = n01a; c01b = n01b; c11a = n11a; c11b = n11b;
        }
    }

    // ---- store partial tile-local dense: part[half][tile][e][32] ----
    float* pslot = part + ((size_t)half * NTILE + tile) * PSLOT;
#pragma unroll
    for (int r = 0; r < 2; r++)
#pragma unroll
        for (int c = 0; c < 2; c++) {
            floatx4 v;
#pragma unroll
            for (int g = 0; g < 4; g++)
                v[g] = accm[r][c][g] + accc[r][c][g] * (1.0f / 2048.0f);
            const int e = wave * 32 + c * 16 + lrow;
            const int t = r * 16 + quad * 4;
            *(floatx4*)(pslot + e * MT + t) = v;
        }
}

// ---------------- epilogue: sum 2 splits, top-2, softmax, me/ce ----------------
__global__ void topk_kernel(const float* __restrict__ part,
                            float* __restrict__ out,
                            float* __restrict__ mece) {
    __shared__ float LG[NE * 68];        // [128][68] token-minor
    __shared__ float tmax[ET], tscale[ET];
    __shared__ int hist[NE];
    const int tid = threadIdx.x;
    const int t0  = blockIdx.x * ET;

    // load + sum split-partials: 4 threads per expert row, 2 passes of 64 experts
    {
        const int q = tid & 3;
        const size_t gtile = (size_t)(blockIdx.x * 2 + (q >> 1));
#pragma unroll
        for (int pass = 0; pass < 2; pass++) {
            const int e = (tid >> 2) + pass * 64;
            const size_t boff = gtile * PSLOT + e * MT + (q & 1) * 16;
            float* dst = LG + e * 68 + q * 16;
#pragma unroll
            for (int j = 0; j < 16; j += 4) {
                float4 s0 = *(const float4*)(part + 0 * NTILE * PSLOT + boff + j);
                float4 s1 = *(const float4*)(part + 1 * NTILE * PSLOT + boff + j);
                float4 s = {s0.x + s1.x, s0.y + s1.y, s0.z + s1.z, s0.w + s1.w};
                *(float4*)(dst + j) = s;
            }
        }
    }
    if (tid < NE) hist[tid] = 0;
    __syncthreads();

    // per-token top-2 + gate softmax (64 threads)
    if (tid < ET) {
        const int t = tid;
        float m1 = -1e30f, m2 = -1e30f;
        int i1 = 0, i2 = 0;
        for (int e = 0; e < NE; e++) {
            float v = LG[e * 68 + t];
            if (v > m1) { m2 = m1; i2 = i1; m1 = v; i1 = e; }
            else if (v > m2) { m2 = v; i2 = e; }
        }
        float s = 0.f;
        for (int e = 0; e < NE; e++)
            s += __expf((LG[e * 68 + t] - m1) * (1.0f / TEMP));
        tmax[t] = m1;
        tscale[t] = 1.0f / s;
        atomicAdd(&hist[i1], 1);

        const int tg = t0 + t;
        out[tg * 2 + 0] = (float)i1;
        out[tg * 2 + 1] = (float)i2;
        float d = __expf(m2 - m1);
        float g1 = 1.0f / (1.0f + d);
        out[2 * NTOK + tg * 2 + 0] = g1;
        out[2 * NTOK + tg * 2 + 1] = d * g1;
    }
    __syncthreads();

    // per-expert me partial (128 threads) -> global atomics
    if (tid < NE) {
        const int e = tid;
        float s = 0.f;
#pragma unroll 4
        for (int t = 0; t < ET; t++)
            s += __expf((LG[e * 68 + t] - tmax[t]) * (1.0f / TEMP)) * tscale[t];
        atomicAdd(&mece[e], s);
        atomicAdd(&mece[NE + e], (float)hist[e]);
    }
}

// ---------------- finalize: loss from me/ce (256 floats) ----------------
__global__ void finalize_kernel(const float* __restrict__ mece, float* __restrict__ out) {
    __shared__ float w2[2];
    const int tid = threadIdx.x;   // 128
    float v = mece[tid] * mece[NE + tid] * ((float)NE / (float)NTOK);
#pragma unroll
    for (int off = 32; off; off >>= 1) v += __shfl_down(v, off);
    if ((tid & 63) == 0) w2[tid >> 6] = v;
    __syncthreads();
    if (tid == 0) out[4 * NTOK] = (w2[0] + w2[1]) / (float)NTOK;
}

extern "C" void kernel_launch(void* const* d_in, const int* in_sizes, int n_in,
                              void* d_out, int out_size, void* d_ws, size_t ws_size,
                              hipStream_t stream) {
    (void)in_sizes; (void)n_in; (void)out_size; (void)ws_size;
    const float* inp = (const float*)d_in[0];
    const float* wg  = (const float*)d_in[1];
    float* out = (float*)d_out;

    _Float16* Bp = (_Float16*)d_ws;                          // 2 MB packed B
    float* mece  = (float*)((char*)d_ws + (2u << 20));       // 256 floats: me[128], ce[128]
    float* part  = (float*)((char*)d_ws + (4u << 20));       // 16 MB: [2][512][128][32]

    hipMemsetAsync(mece, 0, 2 * NE * sizeof(float), stream);
    pack_b_kernel<<<256, 256, 0, stream>>>(wg, Bp);
    moe_gemm_kernel<<<NBLK, 256, 0, stream>>>(inp, Bp, part);
    topk_kernel<<<NBLK_EPI, 256, 0, stream>>>(part, out, mece);
    finalize_kernel<<<1, NE, 0, stream>>>(mece, out);
}

// Round 6
// 553.968 us; speedup vs baseline: 1.1147x; 1.0135x over previous
//
#include <hip/hip_runtime.h>

typedef _Float16 half8 __attribute__((ext_vector_type(8)));
typedef __fp16  fp16x2 __attribute__((ext_vector_type(2)));
typedef float floatx4 __attribute__((ext_vector_type(4)));

#define NTOK 16384
#define DM   4096
#define NE   128
#define MT   32                   // tokens per GEMM tile
#define BK   64                   // k per iter
#define KSPLIT 2
#define KHALF (DM / KSPLIT)       // 2048
#define NITER (KHALF / BK)        // 32 (even, required by 2x unroll)
#define NTILE (NTOK / MT)         // 512
#define NBLK  (NTILE * KSPLIT)    // 1024
#define ET   64                   // tokens per epilogue block
#define NBLK_EPI (NTOK / ET)      // 256
#define TEMP 0.3f
#define PSLOT (MT * NE)           // 4096 floats per (split, tile) partial

// ---------------- prep: pack wg into MFMA b-fragment order, f16x2 split ----------------
__global__ void pack_b_kernel(const float* __restrict__ wg, _Float16* __restrict__ Bp) {
    int gtid = blockIdx.x * blockDim.x + threadIdx.x;
    int l  = gtid & 63;
    int tg = gtid >> 6;
    int g  = tg & 7;
    int kc = tg >> 3;
    const float* src = wg + (size_t)(g * 16 + (l & 15)) * DM + kc * 32 + (l >> 4) * 8;
    float4 v0 = *(const float4*)src;
    float4 v1 = *(const float4*)(src + 4);
    float f[8] = {v0.x, v0.y, v0.z, v0.w, v1.x, v1.y, v1.z, v1.w};
    half8 h1, h2;
#pragma unroll
    for (int j = 0; j < 8; j++) {
        h1[j] = (_Float16)f[j];
        h2[j] = (_Float16)((f[j] - (float)h1[j]) * 2048.0f);
    }
    char* dst = (char*)Bp + (size_t)tg * 2048 + l * 16;
    *(half8*)dst = h1;
    *(half8*)(dst + 1024) = h2;
}

// ---------------- split-f16 convert: packed RTZ, residual captured in lo ----------------
__device__ __forceinline__ void cvt8(float4 a, float4 b, half8* h1, half8* h2) {
    float f[8] = {a.x, a.y, a.z, a.w, b.x, b.y, b.z, b.w};
    half8 H1, H2;
#pragma unroll
    for (int j = 0; j < 8; j += 2) {
        fp16x2 p = __builtin_amdgcn_cvt_pkrtz(f[j], f[j + 1]);
        H1[j] = (_Float16)p.x; H1[j + 1] = (_Float16)p.y;
        float r0 = (f[j]     - (float)p.x) * 2048.0f;
        float r1 = (f[j + 1] - (float)p.y) * 2048.0f;
        fp16x2 q = __builtin_amdgcn_cvt_pkrtz(r0, r1);
        H2[j] = (_Float16)q.x; H2[j + 1] = (_Float16)q.y;
    }
    *h1 = H1; *h2 = H2;
}

// One 64-wide K-step for iteration J; consumes A-set (4 float4), refills it for J+2.
// Order: B loads (16) -> cvt ks0 -> A-prefetch ks0 -> MFMA ks0 -> cvt ks1 -> A-pf ks1 -> MFMA ks1.
#define GBODY(J, PK0A, PK0B, PK1A, PK1B)                                                      \
  {                                                                                           \
    const char* bit = bT + (size_t)(J) * 32768;                                               \
    half8 b1[2][4], b2[2][4];                                                                 \
    _Pragma("unroll") for (int ks = 0; ks < 2; ++ks)                                          \
    _Pragma("unroll") for (int c = 0; c < 4; ++c) {                                           \
        b1[ks][c] = *(const half8*)(bit + ks * 16384 + c * 2048);                             \
        b2[ks][c] = *(const half8*)(bit + ks * 16384 + c * 2048 + 1024);                      \
    }                                                                                         \
    const float* ap = aB + (size_t)(((J) + 2 < NITER) ? ((J) + 2) * BK : 0);                  \
    half8 a1k, a2k;                                                                           \
    cvt8(PK0A, PK0B, &a1k, &a2k);                                                             \
    PK0A = *(const float4*)(ap);                                                              \
    PK0B = *(const float4*)(ap + 4);                                                          \
    _Pragma("unroll") for (int c = 0; c < 4; ++c) {                                           \
        accm[c] = __builtin_amdgcn_mfma_f32_16x16x32_f16(a1k, b1[0][c], accm[c], 0, 0, 0);    \
        accc[c] = __builtin_amdgcn_mfma_f32_16x16x32_f16(a1k, b2[0][c], accc[c], 0, 0, 0);    \
        accc[c] = __builtin_amdgcn_mfma_f32_16x16x32_f16(a2k, b1[0][c], accc[c], 0, 0, 0);    \
    }                                                                                         \
    cvt8(PK1A, PK1B, &a1k, &a2k);                                                             \
    PK1A = *(const float4*)(ap + 32);                                                         \
    PK1B = *(const float4*)(ap + 36);                                                         \
    _Pragma("unroll") for (int c = 0; c < 4; ++c) {                                           \
        accm[c] = __builtin_amdgcn_mfma_f32_16x16x32_f16(a1k, b1[1][c], accm[c], 0, 0, 0);    \
        accc[c] = __builtin_amdgcn_mfma_f32_16x16x32_f16(a1k, b2[1][c], accc[c], 0, 0, 0);    \
        accc[c] = __builtin_amdgcn_mfma_f32_16x16x32_f16(a2k, b1[1][c], accc[c], 0, 0, 0);    \
    }                                                                                         \
  }

// ---------------- main GEMM: barrier-free, LDS-free, depth-2 A prefetch ----------------
__launch_bounds__(256, 2)
__global__ void moe_gemm_kernel(const float* __restrict__ A,
                                const _Float16* __restrict__ Bp,
                                float* __restrict__ part) {
    const int tid  = threadIdx.x;
    const int wave = tid >> 6;
    const int lane = tid & 63;
    const int quad = lane >> 4;
    const int lrow = lane & 15;
    const int tile = blockIdx.x & (NTILE - 1);
    const int half = blockIdx.x >> 9;          // k-split 0/1
    const int tok0 = tile * MT;

    // wave tile: 16 tokens x 64 experts.  tokens: tok0 + (wave&1)*16; experts: (wave>>1)*64
    const float* aB = A + (size_t)(tok0 + (wave & 1) * 16 + lrow) * DM + half * KHALF + quad * 8;
    const char*  bT = (const char*)Bp + ((size_t)half << 20) + ((size_t)(wave >> 1) << 13) + lane * 16;

    floatx4 accm[4], accc[4];
#pragma unroll
    for (int c = 0; c < 4; c++) {
        accm[c] = (floatx4){0.f, 0.f, 0.f, 0.f};
        accc[c] = (floatx4){0.f, 0.f, 0.f, 0.f};
    }

    // prologue: prefetch A fragments for it=0 (set0) and it=1 (set1)
    float4 A00 = *(const float4*)(aB);
    float4 A01 = *(const float4*)(aB + 4);
    float4 A02 = *(const float4*)(aB + 32);
    float4 A03 = *(const float4*)(aB + 36);
    float4 A10 = *(const float4*)(aB + 64);
    float4 A11 = *(const float4*)(aB + 68);
    float4 A12 = *(const float4*)(aB + 96);
    float4 A13 = *(const float4*)(aB + 100);

#pragma unroll 1
    for (int it = 0; it < NITER; it += 2) {
        GBODY(it,     A00, A01, A02, A03)
        GBODY(it + 1, A10, A11, A12, A13)
    }

    // ---- store partial tile-local dense: part[half][tile][e][32] ----
    float* pslot = part + ((size_t)half * NTILE + tile) * PSLOT;
#pragma unroll
    for (int c = 0; c < 4; c++) {
        floatx4 v;
#pragma unroll
        for (int g = 0; g < 4; g++)
            v[g] = accm[c][g] + accc[c][g] * (1.0f / 2048.0f);
        const int e = (wave >> 1) * 64 + c * 16 + lrow;
        const int t = (wave & 1) * 16 + quad * 4;
        *(floatx4*)(pslot + e * MT + t) = v;
    }
}

// ---------------- epilogue: sum 2 splits, top-2, softmax, me/ce ----------------
__global__ void topk_kernel(const float* __restrict__ part,
                            float* __restrict__ out,
                            float* __restrict__ mece) {
    __shared__ float LG[NE * 68];        // [128][68] token-minor
    __shared__ float tmax[ET], tscale[ET];
    __shared__ int hist[NE];
    const int tid = threadIdx.x;
    const int t0  = blockIdx.x * ET;

    // load + sum split-partials: 4 threads per expert row, 2 passes of 64 experts
    {
        const int q = tid & 3;
        const size_t gtile = (size_t)(blockIdx.x * 2 + (q >> 1));
#pragma unroll
        for (int pass = 0; pass < 2; pass++) {
            const int e = (tid >> 2) + pass * 64;
            const size_t boff = gtile * PSLOT + e * MT + (q & 1) * 16;
            float* dst = LG + e * 68 + q * 16;
#pragma unroll
            for (int j = 0; j < 16; j += 4) {
                float4 s0 = *(const float4*)(part + 0 * NTILE * PSLOT + boff + j);
                float4 s1 = *(const float4*)(part + 1 * NTILE * PSLOT + boff + j);
                float4 s = {s0.x + s1.x, s0.y + s1.y, s0.z + s1.z, s0.w + s1.w};
                *(float4*)(dst + j) = s;
            }
        }
    }
    if (tid < NE) hist[tid] = 0;
    __syncthreads();

    // per-token top-2 + gate softmax (64 threads)
    if (tid < ET) {
        const int t = tid;
        float m1 = -1e30f, m2 = -1e30f;
        int i1 = 0, i2 = 0;
        for (int e = 0; e < NE; e++) {
            float v = LG[e * 68 + t];
            if (v > m1) { m2 = m1; i2 = i1; m1 = v; i1 = e; }
            else if (v > m2) { m2 = v; i2 = e; }
        }
        float s = 0.f;
        for (int e = 0; e < NE; e++)
            s += __expf((LG[e * 68 + t] - m1) * (1.0f / TEMP));
        tmax[t] = m1;
        tscale[t] = 1.0f / s;
        atomicAdd(&hist[i1], 1);

        const int tg = t0 + t;
        out[tg * 2 + 0] = (float)i1;
        out[tg * 2 + 1] = (float)i2;
        float d = __expf(m2 - m1);
        float g1 = 1.0f / (1.0f + d);
        out[2 * NTOK + tg * 2 + 0] = g1;
        out[2 * NTOK + tg * 2 + 1] = d * g1;
    }
    __syncthreads();

    // per-expert me partial (128 threads) -> global atomics
    if (tid < NE) {
        const int e = tid;
        float s = 0.f;
#pragma unroll 4
        for (int t = 0; t < ET; t++)
            s += __expf((LG[e * 68 + t] - tmax[t]) * (1.0f / TEMP)) * tscale[t];
        atomicAdd(&mece[e], s);
        atomicAdd(&mece[NE + e], (float)hist[e]);
    }
}

// ---------------- finalize: loss from me/ce (256 floats) ----------------
__global__ void finalize_kernel(const float* __restrict__ mece, float* __restrict__ out) {
    __shared__ float w2[2];
    const int tid = threadIdx.x;   // 128
    float v = mece[tid] * mece[NE + tid] * ((float)NE / (float)NTOK);
#pragma unroll
    for (int off = 32; off; off >>= 1) v += __shfl_down(v, off);
    if ((tid & 63) == 0) w2[tid >> 6] = v;
    __syncthreads();
    if (tid == 0) out[4 * NTOK] = (w2[0] + w2[1]) / (float)NTOK;
}

extern "C" void kernel_launch(void* const* d_in, const int* in_sizes, int n_in,
                              void* d_out, int out_size, void* d_ws, size_t ws_size,
                              hipStream_t stream) {
    (void)in_sizes; (void)n_in; (void)out_size; (void)ws_size;
    const float* inp = (const float*)d_in[0];
    const float* wg  = (const float*)d_in[1];
    float* out = (float*)d_out;

    _Float16* Bp = (_Float16*)d_ws;                          // 2 MB packed B
    float* mece  = (float*)((char*)d_ws + (2u << 20));       // 256 floats: me[128], ce[128]
    float* part  = (float*)((char*)d_ws + (4u << 20));       // 16 MB: [2][512][128][32]

    (void)hipMemsetAsync(mece, 0, 2 * NE * sizeof(float), stream);
    pack_b_kernel<<<256, 256, 0, stream>>>(wg, Bp);
    moe_gemm_kernel<<<NBLK, 256, 0, stream>>>(inp, Bp, part);
    topk_kernel<<<NBLK_EPI, 256, 0, stream>>>(part, out, mece);
    finalize_kernel<<<1, NE, 0, stream>>>(mece, out);
}

// Round 7
// 502.801 us; speedup vs baseline: 1.2281x; 1.1018x over previous
//
#include <hip/hip_runtime.h>

typedef _Float16 half8 __attribute__((ext_vector_type(8)));
typedef __fp16  fp16x2 __attribute__((ext_vector_type(2)));
typedef float floatx4 __attribute__((ext_vector_type(4)));

#define NTOK 16384
#define DM   4096
#define NE   128
#define MT   32                   // tokens per GEMM tile
#define BK   64                   // k per iter
#define KSPLIT 2
#define KHALF (DM / KSPLIT)       // 2048
#define NITER (KHALF / BK)        // 32
#define NTILE (NTOK / MT)         // 512
#define NBLK  (NTILE * KSPLIT)    // 1024
#define ET   64                   // tokens per epilogue block
#define NBLK_EPI (NTOK / ET)      // 256
#define TEMP 0.3f
#define PSLOT (MT * NE)           // 4096 floats per (split, tile) partial

// ---------------- prep: pack wg into MFMA b-fragment order, f16x2 split ----------------
__global__ void pack_b_kernel(const float* __restrict__ wg, _Float16* __restrict__ Bp) {
    int gtid = blockIdx.x * blockDim.x + threadIdx.x;
    int l  = gtid & 63;
    int tg = gtid >> 6;
    int g  = tg & 7;
    int kc = tg >> 3;
    const float* src = wg + (size_t)(g * 16 + (l & 15)) * DM + kc * 32 + (l >> 4) * 8;
    float4 v0 = *(const float4*)src;
    float4 v1 = *(const float4*)(src + 4);
    float f[8] = {v0.x, v0.y, v0.z, v0.w, v1.x, v1.y, v1.z, v1.w};
    half8 h1, h2;
#pragma unroll
    for (int j = 0; j < 8; j++) {
        h1[j] = (_Float16)f[j];
        h2[j] = (_Float16)((f[j] - (float)h1[j]) * 2048.0f);
    }
    char* dst = (char*)Bp + (size_t)tg * 2048 + l * 16;
    *(half8*)dst = h1;
    *(half8*)(dst + 1024) = h2;
}

// ---------------- split-f16 convert: packed RTZ, residual captured in lo ----------------
__device__ __forceinline__ void cvt8(float4 a, float4 b, half8* h1, half8* h2) {
    float f[8] = {a.x, a.y, a.z, a.w, b.x, b.y, b.z, b.w};
    half8 H1, H2;
#pragma unroll
    for (int j = 0; j < 8; j += 2) {
        fp16x2 p = __builtin_amdgcn_cvt_pkrtz(f[j], f[j + 1]);
        H1[j] = (_Float16)p.x; H1[j + 1] = (_Float16)p.y;
        float r0 = (f[j]     - (float)p.x) * 2048.0f;
        float r1 = (f[j + 1] - (float)p.y) * 2048.0f;
        fp16x2 q = __builtin_amdgcn_cvt_pkrtz(r0, r1);
        H2[j] = (_Float16)q.x; H2[j + 1] = (_Float16)q.y;
    }
    *h1 = H1; *h2 = H2;
}

// 3-MFMA split-f16 product into acc pair c
#define MM(c, A1v, A2v, Hv, Lv)                                                          \
    accm[c] = __builtin_amdgcn_mfma_f32_16x16x32_f16(A1v, Hv, accm[c], 0, 0, 0);         \
    accc[c] = __builtin_amdgcn_mfma_f32_16x16x32_f16(A1v, Lv, accc[c], 0, 0, 0);         \
    accc[c] = __builtin_amdgcn_mfma_f32_16x16x32_f16(A2v, Hv, accc[c], 0, 0, 0);

// ---------------- main GEMM: barrier-free, reg-pipelined B (pair double-buffer) --------
__launch_bounds__(256, 2)
__global__ void moe_gemm_kernel(const float* __restrict__ A,
                                const _Float16* __restrict__ Bp,
                                float* __restrict__ part) {
    const int tid  = threadIdx.x;
    const int wave = tid >> 6;
    const int lane = tid & 63;
    const int quad = lane >> 4;
    const int lrow = lane & 15;
    const int tile = blockIdx.x & (NTILE - 1);
    const int half = blockIdx.x >> 9;          // k-split 0/1
    const int tok0 = tile * MT;

    // wave tile: 16 tokens x 64 experts.  tokens: tok0 + (wave&1)*16; experts: (wave>>1)*64
    const float* aB = A + (size_t)(tok0 + (wave & 1) * 16 + lrow) * DM + half * KHALF + quad * 8;
    const char*  bT = (const char*)Bp + ((size_t)half << 20) + ((size_t)(wave >> 1) << 13) + lane * 16;

    floatx4 accm[4], accc[4];
#pragma unroll
    for (int c = 0; c < 4; c++) {
        accm[c] = (floatx4){0.f, 0.f, 0.f, 0.f};
        accc[c] = (floatx4){0.f, 0.f, 0.f, 0.f};
    }

    // A fragments for it=0 (depth-1 prefetch thereafter)
    float4 A00 = *(const float4*)(aB);
    float4 A01 = *(const float4*)(aB + 4);
    float4 A02 = *(const float4*)(aB + 32);
    float4 A03 = *(const float4*)(aB + 36);

    // B pair buffers (named; double-buffered at 2-coltile granularity)
    half8 P0h0, P0l0, P0h1, P0l1;   // buffer 0
    half8 P1h0, P1l0, P1h1, P1l1;   // buffer 1

    // prologue: P0 <- (it=0, ks0, c01)
    P0h0 = *(const half8*)(bT);
    P0l0 = *(const half8*)(bT + 1024);
    P0h1 = *(const half8*)(bT + 2048);
    P0l1 = *(const half8*)(bT + 2048 + 1024);

#pragma unroll 1
    for (int it = 0; it < NITER; ++it) {
        const char* bit = bT + (size_t)it * 32768;
        const char* bnx = bT + ((it + 1 < NITER) ? (size_t)(it + 1) * 32768 : 0);
        const float* ap = aB + ((it + 1 < NITER) ? (size_t)(it + 1) * BK : 0);

        half8 a1k, a2k, a1j, a2j;
        // cvt ks0 A; immediately refill A regs with next iter's ks0 (depth-1)
        cvt8(A00, A01, &a1k, &a2k);
        A00 = *(const float4*)(ap);
        A01 = *(const float4*)(ap + 4);

        // S0: load P1 <- (it, ks0, c23); MFMA P0 = (ks0, c0/c1)
        P1h0 = *(const half8*)(bit + 2 * 2048);
        P1l0 = *(const half8*)(bit + 2 * 2048 + 1024);
        P1h1 = *(const half8*)(bit + 3 * 2048);
        P1l1 = *(const half8*)(bit + 3 * 2048 + 1024);
        MM(0, a1k, a2k, P0h0, P0l0)
        MM(1, a1k, a2k, P0h1, P0l1)

        // S1: load P0 <- (it, ks1, c01); MFMA P1 = (ks0, c2/c3)
        P0h0 = *(const half8*)(bit + 16384);
        P0l0 = *(const half8*)(bit + 16384 + 1024);
        P0h1 = *(const half8*)(bit + 16384 + 2048);
        P0l1 = *(const half8*)(bit + 16384 + 2048 + 1024);
        MM(2, a1k, a2k, P1h0, P1l0)
        MM(3, a1k, a2k, P1h1, P1l1)

        // cvt ks1 A; refill with next iter's ks1
        cvt8(A02, A03, &a1j, &a2j);
        A02 = *(const float4*)(ap + 32);
        A03 = *(const float4*)(ap + 36);

        // S2: load P1 <- (it, ks1, c23); MFMA P0 = (ks1, c0/c1)
        P1h0 = *(const half8*)(bit + 16384 + 2 * 2048);
        P1l0 = *(const half8*)(bit + 16384 + 2 * 2048 + 1024);
        P1h1 = *(const half8*)(bit + 16384 + 3 * 2048);
        P1l1 = *(const half8*)(bit + 16384 + 3 * 2048 + 1024);
        MM(0, a1j, a2j, P0h0, P0l0)
        MM(1, a1j, a2j, P0h1, P0l1)

        // S3: load P0 <- (it+1, ks0, c01); MFMA P1 = (ks1, c2/c3)
        P0h0 = *(const half8*)(bnx);
        P0l0 = *(const half8*)(bnx + 1024);
        P0h1 = *(const half8*)(bnx + 2048);
        P0l1 = *(const half8*)(bnx + 2048 + 1024);
        MM(2, a1j, a2j, P1h0, P1l0)
        MM(3, a1j, a2j, P1h1, P1l1)
    }

    // ---- store partial tile-local dense: part[half][tile][e][32] ----
    float* pslot = part + ((size_t)half * NTILE + tile) * PSLOT;
#pragma unroll
    for (int c = 0; c < 4; c++) {
        floatx4 v;
#pragma unroll
        for (int g = 0; g < 4; g++)
            v[g] = accm[c][g] + accc[c][g] * (1.0f / 2048.0f);
        const int e = (wave >> 1) * 64 + c * 16 + lrow;
        const int t = (wave & 1) * 16 + quad * 4;
        *(floatx4*)(pslot + e * MT + t) = v;
    }
}

// ---------------- epilogue: sum 2 splits, top-2, softmax, me/ce ----------------
__global__ void topk_kernel(const float* __restrict__ part,
                            float* __restrict__ out,
                            float* __restrict__ mece) {
    __shared__ float LG[NE * 68];        // [128][68] token-minor
    __shared__ float tmax[ET], tscale[ET];
    __shared__ int hist[NE];
    const int tid = threadIdx.x;
    const int t0  = blockIdx.x * ET;

    // load + sum split-partials: 4 threads per expert row, 2 passes of 64 experts
    {
        const int q = tid & 3;
        const size_t gtile = (size_t)(blockIdx.x * 2 + (q >> 1));
#pragma unroll
        for (int pass = 0; pass < 2; pass++) {
            const int e = (tid >> 2) + pass * 64;
            const size_t boff = gtile * PSLOT + e * MT + (q & 1) * 16;
            float* dst = LG + e * 68 + q * 16;
#pragma unroll
            for (int j = 0; j < 16; j += 4) {
                float4 s0 = *(const float4*)(part + 0 * NTILE * PSLOT + boff + j);
                float4 s1 = *(const float4*)(part + 1 * NTILE * PSLOT + boff + j);
                float4 s = {s0.x + s1.x, s0.y + s1.y, s0.z + s1.z, s0.w + s1.w};
                *(float4*)(dst + j) = s;
            }
        }
    }
    if (tid < NE) hist[tid] = 0;
    __syncthreads();

    // per-token top-2 + gate softmax (64 threads)
    if (tid < ET) {
        const int t = tid;
        float m1 = -1e30f, m2 = -1e30f;
        int i1 = 0, i2 = 0;
        for (int e = 0; e < NE; e++) {
            float v = LG[e * 68 + t];
            if (v > m1) { m2 = m1; i2 = i1; m1 = v; i1 = e; }
            else if (v > m2) { m2 = v; i2 = e; }
        }
        float s = 0.f;
        for (int e = 0; e < NE; e++)
            s += __expf((LG[e * 68 + t] - m1) * (1.0f / TEMP));
        tmax[t] = m1;
        tscale[t] = 1.0f / s;
        atomicAdd(&hist[i1], 1);

        const int tg = t0 + t;
        out[tg * 2 + 0] = (float)i1;
        out[tg * 2 + 1] = (float)i2;
        float d = __expf(m2 - m1);
        float g1 = 1.0f / (1.0f + d);
        out[2 * NTOK + tg * 2 + 0] = g1;
        out[2 * NTOK + tg * 2 + 1] = d * g1;
    }
    __syncthreads();

    // per-expert me partial (128 threads) -> global atomics
    if (tid < NE) {
        const int e = tid;
        float s = 0.f;
#pragma unroll 4
        for (int t = 0; t < ET; t++)
            s += __expf((LG[e * 68 + t] - tmax[t]) * (1.0f / TEMP)) * tscale[t];
        atomicAdd(&mece[e], s);
        atomicAdd(&mece[NE + e], (float)hist[e]);
    }
}

// ---------------- finalize: loss from me/ce (256 floats) ----------------
__global__ void finalize_kernel(const float* __restrict__ mece, float* __restrict__ out) {
    __shared__ float w2[2];
    const int tid = threadIdx.x;   // 128
    float v = mece[tid] * mece[NE + tid] * ((float)NE / (float)NTOK);
#pragma unroll
    for (int off = 32; off; off >>= 1) v += __shfl_down(v, off);
    if ((tid & 63) == 0) w2[tid >> 6] = v;
    __syncthreads();
    if (tid == 0) out[4 * NTOK] = (w2[0] + w2[1]) / (float)NTOK;
}

extern "C" void kernel_launch(void* const* d_in, const int* in_sizes, int n_in,
                              void* d_out, int out_size, void* d_ws, size_t ws_size,
                              hipStream_t stream) {
    (void)in_sizes; (void)n_in; (void)out_size; (void)ws_size;
    const float* inp = (const float*)d_in[0];
    const float* wg  = (const float*)d_in[1];
    float* out = (float*)d_out;

    _Float16* Bp = (_Float16*)d_ws;                          // 2 MB packed B
    float* mece  = (float*)((char*)d_ws + (2u << 20));       // 256 floats: me[128], ce[128]
    float* part  = (float*)((char*)d_ws + (4u << 20));       // 16 MB: [2][512][128][32]

    (void)hipMemsetAsync(mece, 0, 2 * NE * sizeof(float), stream);
    pack_b_kernel<<<256, 256, 0, stream>>>(wg, Bp);
    moe_gemm_kernel<<<NBLK, 256, 0, stream>>>(inp, Bp, part);
    topk_kernel<<<NBLK_EPI, 256, 0, stream>>>(part, out, mece);
    finalize_kernel<<<1, NE, 0, stream>>>(mece, out);
}